// Round 1
// baseline (760.756 us; speedup 1.0000x reference)
//
#include <hip/hip_runtime.h>

typedef unsigned short u16;
typedef __attribute__((ext_vector_type(8))) short short8;
typedef __attribute__((ext_vector_type(4))) float f32x4;

#define MFMA16(a, b, c) __builtin_amdgcn_mfma_f32_16x16x32_bf16(a, b, c, 0, 0, 0)

__device__ __forceinline__ u16 f2bf(float f) {
    unsigned int u = __builtin_bit_cast(unsigned int, f);
    u += 0x7fffu + ((u >> 16) & 1u);
    return (u16)(u >> 16);
}
__device__ __forceinline__ float bf2f(u16 h) {
    unsigned int u = ((unsigned int)h) << 16;
    return __builtin_bit_cast(float, u);
}

// ---------------------------------------------------------------------------
// repack: weights -> bf16 transposed [N][K]; biases -> concat [768]
// ---------------------------------------------------------------------------
__global__ __launch_bounds__(256) void repack_kernel(
    const float* __restrict__ wq, const float* __restrict__ wk, const float* __restrict__ wv,
    const float* __restrict__ bq, const float* __restrict__ bk, const float* __restrict__ bv,
    const float* __restrict__ w1, const float* __restrict__ w2,
    u16* __restrict__ wqkvT, u16* __restrict__ w1T, u16* __restrict__ w2T,
    float* __restrict__ bqkv)
{
    long idx = (long)blockIdx.x * 256 + threadIdx.x;
    const long NQ = 4L * 768 * 256;
    const long N1 = 4L * 512 * 256;
    const long N2 = 4L * 256 * 512;
    const long NB = 4L * 768;
    if (idx < NQ) {
        long l = idx / (768 * 256); long r = idx % (768 * 256);
        long n = r / 256, k = r % 256;
        float v;
        if (n < 256)      v = wq[(l * 256 + k) * 256 + n];
        else if (n < 512) v = wk[(l * 256 + k) * 256 + (n - 256)];
        else              v = wv[(l * 256 + k) * 256 + (n - 512)];
        wqkvT[idx] = f2bf(v);
    } else if ((idx -= NQ) < N1) {
        long l = idx / (512 * 256); long r = idx % (512 * 256);
        long n = r / 256, k = r % 256;
        w1T[idx] = f2bf(w1[(l * 256 + k) * 512 + n]);
    } else if ((idx -= N1) < N2) {
        long l = idx / (256 * 512); long r = idx % (256 * 512);
        long n = r / 512, k = r % 512;
        w2T[idx] = f2bf(w2[(l * 512 + k) * 256 + n]);
    } else if ((idx -= N2) < NB) {
        long l = idx / 768; long n = idx % 768;
        float v = (n < 256) ? bq[l * 256 + n]
                : (n < 512) ? bk[l * 256 + (n - 256)]
                            : bv[l * 256 + (n - 512)];
        bqkv[l * 768 + n] = v;
    }
}

// ---------------------------------------------------------------------------
// x convert: input fp32 -> fp32 master copy + bf16 copy
// ---------------------------------------------------------------------------
__global__ __launch_bounds__(256) void xconv_kernel(
    const float* __restrict__ xin, float* __restrict__ xf, u16* __restrict__ xb)
{
    long idx = (long)blockIdx.x * 256 + threadIdx.x;
    if (idx < 4096L * 256) {
        float v = xin[idx];
        xf[idx] = v;
        xb[idx] = f2bf(v);
    }
}

// ---------------------------------------------------------------------------
// v transpose: qkv[.][512+hd] -> vt[b*256+hd][n]   (vt: [512][2048] bf16)
// ---------------------------------------------------------------------------
__global__ __launch_bounds__(256) void vtrans_kernel(
    const u16* __restrict__ qkv, u16* __restrict__ vt)
{
    long idx = (long)blockIdx.x * 256 + threadIdx.x;
    if (idx < 2L * 2048 * 256) {
        long b = idx / (2048L * 256);
        long r = idx % (2048L * 256);
        long n = r / 256, hd = r % 256;
        vt[(b * 256 + hd) * 2048 + n] = qkv[(b * 2048 + n) * 768 + 512 + hd];
    }
}

// ---------------------------------------------------------------------------
// GEMM: C[M,N] = A[M,K](bf16) @ BT[N,K](bf16)^T + bias, optional relu,
// out bf16 or f32.  Block = 4 waves (2x2), wave tile 64x64.
// ---------------------------------------------------------------------------
template <bool RELU, bool OUTF32>
__global__ __launch_bounds__(256) void gemm_kernel(
    const u16* __restrict__ A, const u16* __restrict__ BT,
    const float* __restrict__ bias, void* __restrict__ outp,
    int M, int N, int K)
{
    int w = threadIdx.x >> 6, lane = threadIdx.x & 63;
    int wr = w >> 1, wc = w & 1;
    int m0 = blockIdx.x * 128 + wr * 64;
    int n0 = blockIdx.y * 128 + wc * 64;
    int l16 = lane & 15, lhi = lane >> 4;

    f32x4 acc[4][4];
#pragma unroll
    for (int i = 0; i < 4; i++)
#pragma unroll
        for (int j = 0; j < 4; j++) acc[i][j] = (f32x4){0.f, 0.f, 0.f, 0.f};

    const u16* Ap = A + (size_t)(m0 + l16) * K + lhi * 8;
    const u16* Bp = BT + (size_t)(n0 + l16) * K + lhi * 8;

    for (int k = 0; k < K; k += 32) {
        short8 a[4], b[4];
#pragma unroll
        for (int i = 0; i < 4; i++) a[i] = *(const short8*)(Ap + (size_t)i * 16 * K + k);
#pragma unroll
        for (int j = 0; j < 4; j++) b[j] = *(const short8*)(Bp + (size_t)j * 16 * K + k);
#pragma unroll
        for (int i = 0; i < 4; i++)
#pragma unroll
            for (int j = 0; j < 4; j++) acc[i][j] = MFMA16(a[i], b[j], acc[i][j]);
    }

#pragma unroll
    for (int i = 0; i < 4; i++)
#pragma unroll
        for (int j = 0; j < 4; j++) {
            int n = n0 + j * 16 + l16;
            float bs = bias[n];
#pragma unroll
            for (int r = 0; r < 4; r++) {
                int m = m0 + i * 16 + lhi * 4 + r;
                float v = acc[i][j][r] + bs;
                if (RELU) v = fmaxf(v, 0.f);
                if (OUTF32) ((float*)outp)[(size_t)m * N + n] = v;
                else        ((u16*)outp)[(size_t)m * N + n] = f2bf(v);
            }
        }
}

// ---------------------------------------------------------------------------
// Flash attention.  Grid (M/64, B*H), 256 threads = 4 waves x 16 q-rows.
// qkv: [4096][768] bf16 (q|k|v), vt: [512][2048] bf16, out: [4096][256] f32
// ---------------------------------------------------------------------------
__global__ __launch_bounds__(256) void attn_kernel(
    const u16* __restrict__ qkv, const u16* __restrict__ vt,
    const float* __restrict__ coords, const float* __restrict__ alpha,
    int layer, float* __restrict__ outp)
{
    int w = threadIdx.x >> 6, lane = threadIdx.x & 63;
    int bh = blockIdx.y; int b = bh >> 3, h = bh & 7;
    int m0 = blockIdx.x * 64 + w * 16;
    int l16 = lane & 15, lhi = lane >> 4;
    const float scale = 0.1767766953f; // 1/sqrt(32)
    float al = alpha[layer];

    // q fragment (A-layout): row l16, k = lhi*8..+7
    short8 qf = *(const short8*)(qkv + (size_t)(b * 2048 + m0 + l16) * 768 + h * 32 + lhi * 8);

    // coords of this lane's 4 output rows
    float cq[4][3];
#pragma unroll
    for (int r = 0; r < 4; r++) {
        int m = m0 + lhi * 4 + r;
        const float* c = coords + (size_t)(b * 2048 + m) * 3;
        cq[r][0] = c[0]; cq[r][1] = c[1]; cq[r][2] = c[2];
    }

    f32x4 oacc[2];
    oacc[0] = (f32x4){0.f, 0.f, 0.f, 0.f};
    oacc[1] = (f32x4){0.f, 0.f, 0.f, 0.f};
    float mrow[4] = {-1e30f, -1e30f, -1e30f, -1e30f};
    float lrow[4] = {0.f, 0.f, 0.f, 0.f};

    __shared__ u16 plds[4][2][16 * 128];

    const u16* kbase = qkv + 256 + h * 32 + lhi * 8;
    const u16* vbase = vt + (size_t)(b * 256 + h * 32 + l16) * 2048;

    for (int nb = 0; nb < 16; nb++) {
        int n0 = nb * 128;
        float sf[8][4];
#pragma unroll
        for (int t = 0; t < 8; t++) {
            int nt = n0 + t * 16;
            short8 kf = *(const short8*)(kbase + (size_t)(b * 2048 + nt + l16) * 768);
            f32x4 z = (f32x4){0.f, 0.f, 0.f, 0.f};
            f32x4 s = MFMA16(qf, kf, z);
            const float* cn = coords + (size_t)(b * 2048 + nt + l16) * 3;
            float c0 = cn[0], c1 = cn[1], c2 = cn[2];
#pragma unroll
            for (int r = 0; r < 4; r++) {
                float g = cq[r][0] * c0 + cq[r][1] * c1 + cq[r][2] * c2;
                sf[t][r] = s[r] * scale + al * g;
            }
        }
        // row max over this 128-col block
        float tmax[4];
#pragma unroll
        for (int r = 0; r < 4; r++) {
            float v = sf[0][r];
#pragma unroll
            for (int t = 1; t < 8; t++) v = fmaxf(v, sf[t][r]);
            tmax[r] = v;
        }
#pragma unroll
        for (int off = 1; off < 16; off <<= 1)
#pragma unroll
            for (int r = 0; r < 4; r++) tmax[r] = fmaxf(tmax[r], __shfl_xor(tmax[r], off, 64));

        float corr[4];
#pragma unroll
        for (int r = 0; r < 4; r++) {
            float mn = fmaxf(mrow[r], tmax[r]);
            corr[r] = __expf(mrow[r] - mn);
            mrow[r] = mn;
        }
#pragma unroll
        for (int d = 0; d < 2; d++)
#pragma unroll
            for (int r = 0; r < 4; r++) oacc[d][r] *= corr[r];

        float rs[4] = {0.f, 0.f, 0.f, 0.f};
#pragma unroll
        for (int t = 0; t < 8; t++)
#pragma unroll
            for (int r = 0; r < 4; r++) {
                float p = __expf(sf[t][r] - mrow[r]);
                sf[t][r] = p;
                rs[r] += p;
            }
#pragma unroll
        for (int off = 1; off < 16; off <<= 1)
#pragma unroll
            for (int r = 0; r < 4; r++) rs[r] += __shfl_xor(rs[r], off, 64);
#pragma unroll
        for (int r = 0; r < 4; r++) lrow[r] = lrow[r] * corr[r] + rs[r];

        // write P (bf16) to LDS, XOR-swizzled: P[row][col] at
        // u16 index row*128 + ((col>>3 ^ row)<<3) + (col&7)
        u16* pl = plds[w][nb & 1];
#pragma unroll
        for (int t = 0; t < 8; t++) {
            int slot = t * 2 + (l16 >> 3);
            int c7 = l16 & 7;
#pragma unroll
            for (int r = 0; r < 4; r++) {
                int row = lhi * 4 + r;
                pl[row * 128 + ((slot ^ row) << 3) + c7] = f2bf(sf[t][r]);
            }
        }
        asm volatile("s_waitcnt lgkmcnt(0)" ::: "memory");

        // PV: A = P[16x32 chunk] from LDS, B = vt fragment
#pragma unroll
        for (int kk = 0; kk < 4; kk++) {
            int slotr = kk * 4 + lhi;
            short8 pf = *(const short8*)(pl + l16 * 128 + ((slotr ^ l16) << 3));
#pragma unroll
            for (int dt = 0; dt < 2; dt++) {
                short8 vf = *(const short8*)(vbase + (size_t)dt * 16 * 2048 + n0 + kk * 32 + lhi * 8);
                oacc[dt] = MFMA16(pf, vf, oacc[dt]);
            }
        }
    }

    // normalize + store fp32
    float inv[4];
#pragma unroll
    for (int r = 0; r < 4; r++) inv[r] = 1.f / lrow[r];
#pragma unroll
    for (int dt = 0; dt < 2; dt++)
#pragma unroll
        for (int r = 0; r < 4; r++) {
            int m = m0 + lhi * 4 + r;
            outp[(size_t)(b * 2048 + m) * 256 + h * 32 + dt * 16 + l16] = oacc[dt][r] * inv[r];
        }
}

// ---------------------------------------------------------------------------
// Residual + LayerNorm: out = LN(xin + add)*g + b, write fp32 + bf16
// One wave per row (D=256, 4 cols/lane).
// ---------------------------------------------------------------------------
__global__ __launch_bounds__(256) void ln_kernel(
    const float* __restrict__ xin, const float* __restrict__ add,
    const float* __restrict__ g, const float* __restrict__ bb,
    float* __restrict__ outf, u16* __restrict__ outb)
{
    int w = threadIdx.x >> 6, lane = threadIdx.x & 63;
    int row = blockIdx.x * 4 + w;
    size_t base = (size_t)row * 256 + lane * 4;
    float4 xv = *(const float4*)(xin + base);
    float4 av = *(const float4*)(add + base);
    float s0 = xv.x + av.x, s1 = xv.y + av.y, s2 = xv.z + av.z, s3 = xv.w + av.w;
    float sum = s0 + s1 + s2 + s3;
    float sq = s0 * s0 + s1 * s1 + s2 * s2 + s3 * s3;
#pragma unroll
    for (int off = 1; off < 64; off <<= 1) {
        sum += __shfl_xor(sum, off, 64);
        sq += __shfl_xor(sq, off, 64);
    }
    float mu = sum * (1.f / 256.f);
    float var = sq * (1.f / 256.f) - mu * mu;
    float rs = rsqrtf(var + 1e-5f);
    float4 gv = *(const float4*)(g + lane * 4);
    float4 bv = *(const float4*)(bb + lane * 4);
    float y0 = (s0 - mu) * rs * gv.x + bv.x;
    float y1 = (s1 - mu) * rs * gv.y + bv.y;
    float y2 = (s2 - mu) * rs * gv.z + bv.z;
    float y3 = (s3 - mu) * rs * gv.w + bv.w;
    float4 yo; yo.x = y0; yo.y = y1; yo.z = y2; yo.w = y3;
    *(float4*)(outf + base) = yo;
    unsigned int p0 = (unsigned int)f2bf(y0) | ((unsigned int)f2bf(y1) << 16);
    unsigned int p1 = (unsigned int)f2bf(y2) | ((unsigned int)f2bf(y3) << 16);
    uint2 pk; pk.x = p0; pk.y = p1;
    *(uint2*)(outb + base) = pk;
}

// ---------------------------------------------------------------------------
extern "C" void kernel_launch(void* const* d_in, const int* in_sizes, int n_in,
                              void* d_out, int out_size, void* d_ws, size_t ws_size,
                              hipStream_t stream)
{
    const float* x_in   = (const float*)d_in[0];
    const float* coords = (const float*)d_in[1];
    const float* wq = (const float*)d_in[2];
    const float* bq = (const float*)d_in[3];
    const float* wk = (const float*)d_in[4];
    const float* bk = (const float*)d_in[5];
    const float* wv = (const float*)d_in[6];
    const float* bv = (const float*)d_in[7];
    const float* alpha = (const float*)d_in[8];
    const float* w1 = (const float*)d_in[9];
    const float* b1 = (const float*)d_in[10];
    const float* w2 = (const float*)d_in[11];
    const float* b2 = (const float*)d_in[12];
    const float* ln1g = (const float*)d_in[13];
    const float* ln1b = (const float*)d_in[14];
    const float* ln2g = (const float*)d_in[15];
    const float* ln2b = (const float*)d_in[16];
    float* out = (float*)d_out;

    char* ws = (char*)d_ws;
    size_t off = 0;
    auto alloc = [&](size_t bytes) -> void* {
        void* p = ws + off;
        off += (bytes + 255) & ~(size_t)255;
        return p;
    };
    float* x_f32 = (float*)alloc(4096UL * 256 * 4);
    u16*   x_bf  = (u16*)  alloc(4096UL * 256 * 2);
    u16*   qkv   = (u16*)  alloc(4096UL * 768 * 2);
    u16*   vt    = (u16*)  alloc(512UL * 2048 * 2);
    float* attn  = (float*)alloc(4096UL * 256 * 4);
    u16*   mid   = (u16*)  alloc(4096UL * 512 * 2);
    float* ffn   = (float*)alloc(4096UL * 256 * 4);
    u16*   wqkvT = (u16*)  alloc(4UL * 768 * 256 * 2);
    u16*   w1T   = (u16*)  alloc(4UL * 512 * 256 * 2);
    u16*   w2T   = (u16*)  alloc(4UL * 256 * 512 * 2);
    float* bqkv  = (float*)alloc(4UL * 768 * 4);

    repack_kernel<<<7180, 256, 0, stream>>>(wq, wk, wv, bq, bk, bv, w1, w2,
                                            wqkvT, w1T, w2T, bqkv);
    xconv_kernel<<<4096, 256, 0, stream>>>(x_in, x_f32, x_bf);

    for (int i = 0; i < 4; i++) {
        gemm_kernel<false, false><<<dim3(32, 6), 256, 0, stream>>>(
            x_bf, wqkvT + (size_t)i * 768 * 256, bqkv + i * 768, qkv, 4096, 768, 256);
        vtrans_kernel<<<4096, 256, 0, stream>>>(qkv, vt);
        attn_kernel<<<dim3(32, 16), 256, 0, stream>>>(qkv, vt, coords, alpha, i, attn);
        ln_kernel<<<1024, 256, 0, stream>>>(x_f32, attn, ln1g + i * 256, ln1b + i * 256,
                                            x_f32, x_bf);
        gemm_kernel<true, false><<<dim3(32, 4), 256, 0, stream>>>(
            x_bf, w1T + (size_t)i * 512 * 256, b1 + i * 512, mid, 4096, 512, 256);
        gemm_kernel<false, true><<<dim3(32, 2), 256, 0, stream>>>(
            mid, w2T + (size_t)i * 256 * 512, b2 + i * 256, ffn, 4096, 256, 512);
        ln_kernel<<<1024, 256, 0, stream>>>(x_f32, ffn, ln2g + i * 256, ln2b + i * 256,
                                            (i == 3) ? out : x_f32, x_bf);
    }
}

// Round 2
// 529.560 us; speedup vs baseline: 1.4366x; 1.4366x over previous
//
#include <hip/hip_runtime.h>

typedef unsigned short u16;
typedef __attribute__((ext_vector_type(8))) short short8;
typedef __attribute__((ext_vector_type(4))) float f32x4;

#define MFMA16(a, b, c) __builtin_amdgcn_mfma_f32_16x16x32_bf16(a, b, c, 0, 0, 0)

#define LOG2E 1.4426950408889634f
// q-side fold: (1/sqrt(32)) * log2(e)
#define QSCALE 0.25506038410312156f

__device__ __forceinline__ u16 f2bf(float f) {
    unsigned int u = __builtin_bit_cast(unsigned int, f);
    u += 0x7fffu + ((u >> 16) & 1u);
    return (u16)(u >> 16);
}

// ---------------------------------------------------------------------------
// repack: weights -> bf16 transposed [N][K]; q-weights pre-scaled by QSCALE
// ---------------------------------------------------------------------------
__global__ __launch_bounds__(256) void repack_kernel(
    const float* __restrict__ wq, const float* __restrict__ wk, const float* __restrict__ wv,
    const float* __restrict__ bq, const float* __restrict__ bk, const float* __restrict__ bv,
    const float* __restrict__ w1, const float* __restrict__ w2,
    u16* __restrict__ wqkvT, u16* __restrict__ w1T, u16* __restrict__ w2T,
    float* __restrict__ bqkv)
{
    long idx = (long)blockIdx.x * 256 + threadIdx.x;
    const long NQ = 4L * 768 * 256;
    const long N1 = 4L * 512 * 256;
    const long N2 = 4L * 256 * 512;
    const long NB = 4L * 768;
    if (idx < NQ) {
        long l = idx / (768 * 256); long r = idx % (768 * 256);
        long n = r / 256, k = r % 256;
        float v;
        if (n < 256)      v = wq[(l * 256 + k) * 256 + n] * QSCALE;
        else if (n < 512) v = wk[(l * 256 + k) * 256 + (n - 256)];
        else              v = wv[(l * 256 + k) * 256 + (n - 512)];
        wqkvT[idx] = f2bf(v);
    } else if ((idx -= NQ) < N1) {
        long l = idx / (512 * 256); long r = idx % (512 * 256);
        long n = r / 256, k = r % 256;
        w1T[idx] = f2bf(w1[(l * 256 + k) * 512 + n]);
    } else if ((idx -= N1) < N2) {
        long l = idx / (256 * 512); long r = idx % (256 * 512);
        long n = r / 512, k = r % 512;
        w2T[idx] = f2bf(w2[(l * 512 + k) * 256 + n]);
    } else if ((idx -= N2) < NB) {
        long l = idx / 768; long n = idx % 768;
        float v = (n < 256) ? bq[l * 256 + n] * QSCALE
                : (n < 512) ? bk[l * 256 + (n - 256)]
                            : bv[l * 256 + (n - 512)];
        bqkv[l * 768 + n] = v;
    }
}

// ---------------------------------------------------------------------------
// x convert: input fp32 -> fp32 master copy + bf16 copy
// ---------------------------------------------------------------------------
__global__ __launch_bounds__(256) void xconv_kernel(
    const float* __restrict__ xin, float* __restrict__ xf, u16* __restrict__ xb)
{
    long idx = (long)blockIdx.x * 256 + threadIdx.x;
    if (idx < 4096L * 256) {
        float v = xin[idx];
        xf[idx] = v;
        xb[idx] = f2bf(v);
    }
}

// ---------------------------------------------------------------------------
// prep per layer: V transpose (vt[b][h*32+d][n]) + kcoord rows
// kcoord[b][n][16] bf16 = {alpha*c0, alpha*c1, alpha*c2, 0...}
// grid (2048/64, 16), block 256
// ---------------------------------------------------------------------------
__global__ __launch_bounds__(256) void prep_kernel(
    const u16* __restrict__ qkv, const float* __restrict__ coords,
    const float* __restrict__ alpha, int layer,
    u16* __restrict__ vt, u16* __restrict__ kcoord)
{
    int bh = blockIdx.y, b = bh >> 3, h = bh & 7;
    int m0 = blockIdx.x * 64;
    int tid = threadIdx.x;
    int n = m0 + (tid & 63);
    int dbase = tid >> 6; // 0..3
#pragma unroll
    for (int pass = 0; pass < 8; pass++) {
        int d = dbase * 8 + pass;
        vt[((size_t)(b * 256 + h * 32 + d)) * 2048 + n] =
            qkv[((size_t)(b * 2048 + n)) * 768 + 512 + h * 32 + d];
    }
    if (h == 0 && tid < 64) {
        float a = alpha[layer];
        int nn = m0 + tid;
        const float* c = coords + ((size_t)b * 2048 + nn) * 3;
        u16 r0 = f2bf(c[0] * a), r1 = f2bf(c[1] * a), r2 = f2bf(c[2] * a);
        uint4 lo; lo.x = (unsigned)r0 | ((unsigned)r1 << 16); lo.y = (unsigned)r2; lo.z = 0; lo.w = 0;
        uint4 hi; hi.x = 0; hi.y = 0; hi.z = 0; hi.w = 0;
        uint4* dst = (uint4*)(kcoord + ((size_t)b * 2048 + nn) * 16);
        dst[0] = lo; dst[1] = hi;
    }
}

// ---------------------------------------------------------------------------
// GEMM: C[M,N] = A[M,K](bf16) @ BT[N,K]^T + bias; block 64x64 (4 waves 32x32)
// ---------------------------------------------------------------------------
template <bool RELU, bool OUTF32>
__global__ __launch_bounds__(256) void gemm_kernel(
    const u16* __restrict__ A, const u16* __restrict__ BT,
    const float* __restrict__ bias, void* __restrict__ outp,
    int M, int N, int K)
{
    int w = threadIdx.x >> 6, lane = threadIdx.x & 63;
    int wr = w >> 1, wc = w & 1;
    int m0 = blockIdx.x * 64 + wr * 32;
    int n0 = blockIdx.y * 64 + wc * 32;
    int l16 = lane & 15, lhi = lane >> 4;

    f32x4 acc[2][2];
#pragma unroll
    for (int i = 0; i < 2; i++)
#pragma unroll
        for (int j = 0; j < 2; j++) acc[i][j] = (f32x4){0.f, 0.f, 0.f, 0.f};

    const u16* Ap = A + (size_t)(m0 + l16) * K + lhi * 8;
    const u16* Bp = BT + (size_t)(n0 + l16) * K + lhi * 8;

    for (int k = 0; k < K; k += 32) {
        short8 a0 = *(const short8*)(Ap + k);
        short8 a1 = *(const short8*)(Ap + (size_t)16 * K + k);
        short8 b0 = *(const short8*)(Bp + k);
        short8 b1 = *(const short8*)(Bp + (size_t)16 * K + k);
        acc[0][0] = MFMA16(a0, b0, acc[0][0]);
        acc[0][1] = MFMA16(a0, b1, acc[0][1]);
        acc[1][0] = MFMA16(a1, b0, acc[1][0]);
        acc[1][1] = MFMA16(a1, b1, acc[1][1]);
    }

#pragma unroll
    for (int i = 0; i < 2; i++)
#pragma unroll
        for (int j = 0; j < 2; j++) {
            int n = n0 + j * 16 + l16;
            float bs = bias[n];
#pragma unroll
            for (int r = 0; r < 4; r++) {
                int m = m0 + i * 16 + lhi * 4 + r;
                float v = acc[i][j][r] + bs;
                if (RELU) v = fmaxf(v, 0.f);
                if (OUTF32) ((float*)outp)[(size_t)m * N + n] = v;
                else        ((u16*)outp)[(size_t)m * N + n] = f2bf(v);
            }
        }
}

// ---------------------------------------------------------------------------
// Flash attention, swapped-QK^T. Grid (2048/16, 16), block 64 (1 wave).
// Per wave: 16 q-rows. Scores in log2 domain (constants pre-folded).
// qkv: [4096][768] (q pre-scaled) | vt: [512][2048] | kcoord: [2][2048][16]
// out: [4096][256] f32
// ---------------------------------------------------------------------------
__global__ __launch_bounds__(64) void attn_kernel(
    const u16* __restrict__ qkv, const u16* __restrict__ vt,
    const u16* __restrict__ kcoord, const float* __restrict__ coords,
    float* __restrict__ outp)
{
    int lane = threadIdx.x;
    int bh = blockIdx.y, b = bh >> 3, h = bh & 7;
    int m0 = blockIdx.x * 16;
    int l16 = lane & 15, lhi = lane >> 4;

    __shared__ u16 plds[2][16 * 128];
    __shared__ float olds[16 * 32];

    // Q fragments (B-operand): lane holds q-row m0+l16, k-dims lhi*8..
    short8 qlo = *(const short8*)(qkv + (size_t)(b * 2048 + m0 + l16) * 768 + h * 32 + lhi * 8);
    short8 qhi = {0, 0, 0, 0, 0, 0, 0, 0};
    {
        const float* c = coords + (size_t)(b * 2048 + m0 + l16) * 3;
        if (lhi == 0) {
            qhi[0] = (short)f2bf(c[0] * LOG2E);
            qhi[1] = (short)f2bf(c[1] * LOG2E);
            qhi[2] = (short)f2bf(c[2] * LOG2E);
        }
    }

    f32x4 oacc[2];
    oacc[0] = (f32x4){0.f, 0.f, 0.f, 0.f};
    oacc[1] = (f32x4){0.f, 0.f, 0.f, 0.f};
    float mrow = -1e30f, lrow = 0.f;

    const u16* kbase = qkv + 256 + h * 32 + lhi * 8; // + (b*2048+n)*768
    const u16* kcb = kcoord + lhi * 8;               // + (b*2048+n)*16, lhi<2 only
    const u16* vbase = vt + (size_t)(b * 256 + h * 32 + l16) * 2048;

    for (int nb = 0; nb < 16; nb++) {
        int n0b = nb * 128;
        f32x4 s[8];
#pragma unroll
        for (int t = 0; t < 8; t++) {
            size_t roff = (size_t)(b * 2048 + n0b + t * 16 + l16);
            short8 klo = *(const short8*)(kbase + roff * 768);
            short8 khi = {0, 0, 0, 0, 0, 0, 0, 0};
            if (lhi < 2) khi = *(const short8*)(kcb + roff * 16);
            f32x4 z = (f32x4){0.f, 0.f, 0.f, 0.f};
            z = MFMA16(klo, qlo, z);
            s[t] = MFMA16(khi, qhi, z);
        }
        // lane holds S[n = n0b + t*16 + lhi*4 + r][q = l16] (log2 domain)
        float tm = -1e30f;
#pragma unroll
        for (int t = 0; t < 8; t++) {
            float a = fmaxf(fmaxf(s[t][0], s[t][1]), fmaxf(s[t][2], s[t][3]));
            tm = fmaxf(tm, a);
        }
        tm = fmaxf(tm, __shfl_xor(tm, 16, 64));
        tm = fmaxf(tm, __shfl_xor(tm, 32, 64));
        float mnew = fmaxf(mrow, tm);
        float corr = exp2f(mrow - mnew);
        mrow = mnew;
#pragma unroll
        for (int d = 0; d < 2; d++)
#pragma unroll
            for (int r = 0; r < 4; r++) oacc[d][r] *= corr;

        float rs = 0.f;
#pragma unroll
        for (int t = 0; t < 8; t++) {
#pragma unroll
            for (int r = 0; r < 4; r++) s[t][r] = exp2f(s[t][r] - mrow);
            rs += (s[t][0] + s[t][1]) + (s[t][2] + s[t][3]);
        }
        rs += __shfl_xor(rs, 16, 64);
        rs += __shfl_xor(rs, 32, 64);
        lrow = lrow * corr + rs;

        // P^T -> LDS: row q=l16, n = n0b + t*16 + lhi*4 + r, swizzled slots
        u16* pl = plds[nb & 1];
#pragma unroll
        for (int t = 0; t < 8; t++) {
            unsigned p0, p1;
            asm("v_cvt_pk_bf16_f32 %0, %1, %2" : "=v"(p0) : "v"(s[t][0]), "v"(s[t][1]));
            asm("v_cvt_pk_bf16_f32 %0, %1, %2" : "=v"(p1) : "v"(s[t][2]), "v"(s[t][3]));
            int slot = (t * 2 + (lhi >> 1)) ^ l16;
            uint2 val; val.x = p0; val.y = p1;
            *(uint2*)(pl + l16 * 128 + (slot << 3) + (lhi & 1) * 4) = val;
        }
        asm volatile("s_waitcnt lgkmcnt(0)" ::: "memory");
        __builtin_amdgcn_sched_barrier(0);

        // PV: out^T[d][q] += V^T[d][n] * P^T[n][q]
#pragma unroll
        for (int kk = 0; kk < 4; kk++) {
            short8 pf = *(const short8*)(pl + l16 * 128 + (((kk * 4 + lhi) ^ l16) << 3));
#pragma unroll
            for (int dt = 0; dt < 2; dt++) {
                short8 vf = *(const short8*)(vbase + (size_t)dt * 16 * 2048 + n0b + kk * 32 + lhi * 8);
                oacc[dt] = MFMA16(vf, pf, oacc[dt]);
            }
        }
    }

    float inv = 1.f / lrow;
#pragma unroll
    for (int dt = 0; dt < 2; dt++) {
        f32x4 v = oacc[dt];
#pragma unroll
        for (int r = 0; r < 4; r++) v[r] *= inv;
        *(f32x4*)(olds + l16 * 32 + dt * 16 + lhi * 4) = v;
    }
    asm volatile("s_waitcnt lgkmcnt(0)" ::: "memory");
    __builtin_amdgcn_sched_barrier(0);
#pragma unroll
    for (int p = 0; p < 2; p++) {
        int m = p * 8 + (lane >> 3), c = lane & 7;
        f32x4 v = *(const f32x4*)(olds + m * 32 + c * 4);
        *(f32x4*)(outp + (size_t)(b * 2048 + m0 + m) * 256 + h * 32 + c * 4) = v;
    }
}

// ---------------------------------------------------------------------------
// Residual + LayerNorm
// ---------------------------------------------------------------------------
__global__ __launch_bounds__(256) void ln_kernel(
    const float* __restrict__ xin, const float* __restrict__ add,
    const float* __restrict__ g, const float* __restrict__ bb,
    float* __restrict__ outf, u16* __restrict__ outb)
{
    int w = threadIdx.x >> 6, lane = threadIdx.x & 63;
    int row = blockIdx.x * 4 + w;
    size_t base = (size_t)row * 256 + lane * 4;
    float4 xv = *(const float4*)(xin + base);
    float4 av = *(const float4*)(add + base);
    float s0 = xv.x + av.x, s1 = xv.y + av.y, s2 = xv.z + av.z, s3 = xv.w + av.w;
    float sum = s0 + s1 + s2 + s3;
    float sq = s0 * s0 + s1 * s1 + s2 * s2 + s3 * s3;
#pragma unroll
    for (int off = 1; off < 64; off <<= 1) {
        sum += __shfl_xor(sum, off, 64);
        sq += __shfl_xor(sq, off, 64);
    }
    float mu = sum * (1.f / 256.f);
    float var = sq * (1.f / 256.f) - mu * mu;
    float rs = rsqrtf(var + 1e-5f);
    float4 gv = *(const float4*)(g + lane * 4);
    float4 bv = *(const float4*)(bb + lane * 4);
    float y0 = (s0 - mu) * rs * gv.x + bv.x;
    float y1 = (s1 - mu) * rs * gv.y + bv.y;
    float y2 = (s2 - mu) * rs * gv.z + bv.z;
    float y3 = (s3 - mu) * rs * gv.w + bv.w;
    float4 yo; yo.x = y0; yo.y = y1; yo.z = y2; yo.w = y3;
    *(float4*)(outf + base) = yo;
    unsigned int p0 = (unsigned int)f2bf(y0) | ((unsigned int)f2bf(y1) << 16);
    unsigned int p1 = (unsigned int)f2bf(y2) | ((unsigned int)f2bf(y3) << 16);
    uint2 pk; pk.x = p0; pk.y = p1;
    *(uint2*)(outb + base) = pk;
}

// ---------------------------------------------------------------------------
extern "C" void kernel_launch(void* const* d_in, const int* in_sizes, int n_in,
                              void* d_out, int out_size, void* d_ws, size_t ws_size,
                              hipStream_t stream)
{
    const float* x_in   = (const float*)d_in[0];
    const float* coords = (const float*)d_in[1];
    const float* wq = (const float*)d_in[2];
    const float* bq = (const float*)d_in[3];
    const float* wk = (const float*)d_in[4];
    const float* bk = (const float*)d_in[5];
    const float* wv = (const float*)d_in[6];
    const float* bv = (const float*)d_in[7];
    const float* alpha = (const float*)d_in[8];
    const float* w1 = (const float*)d_in[9];
    const float* b1 = (const float*)d_in[10];
    const float* w2 = (const float*)d_in[11];
    const float* b2 = (const float*)d_in[12];
    const float* ln1g = (const float*)d_in[13];
    const float* ln1b = (const float*)d_in[14];
    const float* ln2g = (const float*)d_in[15];
    const float* ln2b = (const float*)d_in[16];
    float* out = (float*)d_out;

    char* ws = (char*)d_ws;
    size_t off = 0;
    auto alloc = [&](size_t bytes) -> void* {
        void* p = ws + off;
        off += (bytes + 255) & ~(size_t)255;
        return p;
    };
    float* x_f32 = (float*)alloc(4096UL * 256 * 4);
    u16*   x_bf  = (u16*)  alloc(4096UL * 256 * 2);
    u16*   qkv   = (u16*)  alloc(4096UL * 768 * 2);
    u16*   vt    = (u16*)  alloc(512UL * 2048 * 2);
    u16*   kcoord= (u16*)  alloc(2UL * 2048 * 16 * 2);
    float* attnb = (float*)alloc(4096UL * 256 * 4);
    u16*   mid   = (u16*)  alloc(4096UL * 512 * 2);
    float* ffn   = (float*)alloc(4096UL * 256 * 4);
    u16*   wqkvT = (u16*)  alloc(4UL * 768 * 256 * 2);
    u16*   w1T   = (u16*)  alloc(4UL * 512 * 256 * 2);
    u16*   w2T   = (u16*)  alloc(4UL * 256 * 512 * 2);
    float* bqkv  = (float*)alloc(4UL * 768 * 4);

    repack_kernel<<<7180, 256, 0, stream>>>(wq, wk, wv, bq, bk, bv, w1, w2,
                                            wqkvT, w1T, w2T, bqkv);
    xconv_kernel<<<4096, 256, 0, stream>>>(x_in, x_f32, x_bf);

    for (int i = 0; i < 4; i++) {
        gemm_kernel<false, false><<<dim3(64, 12), 256, 0, stream>>>(
            x_bf, wqkvT + (size_t)i * 768 * 256, bqkv + i * 768, qkv, 4096, 768, 256);
        prep_kernel<<<dim3(32, 16), 256, 0, stream>>>(qkv, coords, alpha, i, vt, kcoord);
        attn_kernel<<<dim3(128, 16), 64, 0, stream>>>(qkv, vt, kcoord, coords, attnb);
        ln_kernel<<<1024, 256, 0, stream>>>(x_f32, attnb, ln1g + i * 256, ln1b + i * 256,
                                            x_f32, x_bf);
        gemm_kernel<true, false><<<dim3(64, 8), 256, 0, stream>>>(
            x_bf, w1T + (size_t)i * 512 * 256, b1 + i * 512, mid, 4096, 512, 256);
        gemm_kernel<false, true><<<dim3(64, 4), 256, 0, stream>>>(
            mid, w2T + (size_t)i * 256 * 512, b2 + i * 256, ffn, 4096, 256, 512);
        ln_kernel<<<1024, 256, 0, stream>>>(x_f32, ffn, ln2g + i * 256, ln2b + i * 256,
                                            (i == 3) ? out : x_f32, x_bf);
    }
}